// Round 1
// baseline (91.334 us; speedup 1.0000x reference)
//
#include <hip/hip_runtime.h>

#define HH   512
#define AA   128
#define SB   1024
#define BATCH 2

__device__ __forceinline__ float fast_rcp(float x) { return __builtin_amdgcn_rcpf(x); }
__device__ __forceinline__ float fast_ex2(float x) { return __builtin_amdgcn_exp2f(x); }

// K1: C = lstm(2048x512) @ [w|u](512x256), epilogue exp2(2*log2e * c), split into P,Q.
// BM=32, BN=32, BK=16, 256 threads, 2x2 per thread. grid (64, 8).
__global__ __launch_bounds__(256) void k1_gemm_exp(const float* __restrict__ lstm,
                                                   const float* __restrict__ w,
                                                   const float* __restrict__ u,
                                                   float* __restrict__ P,
                                                   float* __restrict__ Q)
{
    __shared__ float As[16][33];
    __shared__ float Bs[16][33];
    const int bm = blockIdx.x;          // 0..63  (M = 2048, 32 rows each)
    const int bn = blockIdx.y;          // 0..7   (N = 256, 32 cols each)
    const float* Bsrc = (bn < 4) ? w : u;
    float* Obuf      = (bn < 4) ? P : Q;
    const int ncol0 = (bn & 3) * 32;
    const int t = threadIdx.x;
    const int tm = t >> 4;              // 0..15
    const int tn = t & 15;              // 0..15

    float acc00 = 0.f, acc01 = 0.f, acc10 = 0.f, acc11 = 0.f;

    for (int k0 = 0; k0 < HH; k0 += 16) {
        if (t < 128) {
            const int row = t >> 2;             // 0..31
            const int f4  = (t & 3) * 4;        // 0,4,8,12
            const float4 a4 = *(const float4*)&lstm[(size_t)(bm * 32 + row) * HH + k0 + f4];
            As[f4 + 0][row] = a4.x;
            As[f4 + 1][row] = a4.y;
            As[f4 + 2][row] = a4.z;
            As[f4 + 3][row] = a4.w;
        } else {
            const int tt = t - 128;
            const int kk = tt >> 3;             // 0..15
            const int f4 = (tt & 7) * 4;        // 0..28
            const float4 b4 = *(const float4*)&Bsrc[(size_t)(k0 + kk) * AA + ncol0 + f4];
            *(float4*)&Bs[kk][f4] = b4;
        }
        __syncthreads();
        #pragma unroll
        for (int k = 0; k < 16; ++k) {
            const float a0 = As[k][tm * 2 + 0];
            const float a1 = As[k][tm * 2 + 1];
            const float b0 = Bs[k][tn * 2 + 0];
            const float b1 = Bs[k][tn * 2 + 1];
            acc00 = fmaf(a0, b0, acc00);
            acc01 = fmaf(a0, b1, acc01);
            acc10 = fmaf(a1, b0, acc10);
            acc11 = fmaf(a1, b1, acc11);
        }
        __syncthreads();
    }

    const float KK = 2.8853900817779268f;   // 2 * log2(e)
    const int rowg = bm * 32 + tm * 2;
    const int colg = ncol0 + tn * 2;
    Obuf[(size_t)(rowg + 0) * AA + colg + 0] = fast_ex2(KK * acc00);
    Obuf[(size_t)(rowg + 0) * AA + colg + 1] = fast_ex2(KK * acc01);
    Obuf[(size_t)(rowg + 1) * AA + colg + 0] = fast_ex2(KK * acc10);
    Obuf[(size_t)(rowg + 1) * AA + colg + 1] = fast_ex2(KK * acc11);
}

// K2a: e[b,i,j] = V - 2 * sum_a v[a] / (P[b,i,a]*Q[b,j,a] + 1), written raw into attn region.
// grid (4 jchunks, 128 ichunks, 2 b), 256 threads; block covers 8 i-rows x 256 j.
__global__ __launch_bounds__(256) void k2a_escore(const float* __restrict__ P,
                                                  const float* __restrict__ Q,
                                                  const float* __restrict__ v,
                                                  float* __restrict__ e_out)
{
    __shared__ float Plds[8][AA];
    __shared__ float vlds[AA];
    const int b  = blockIdx.z;
    const int i0 = blockIdx.y * 8;
    const int j0 = blockIdx.x * 256;
    const int t  = threadIdx.x;

    {   // stage 8 P rows (1024 floats) + v
        const int r  = t >> 5;            // 0..7
        const int c4 = (t & 31) * 4;      // 0..124
        *(float4*)&Plds[r][c4] = *(const float4*)&P[(size_t)(b * SB + i0 + r) * AA + c4];
        if (t < 32) *(float4*)&vlds[t * 4] = *(const float4*)&v[t * 4];
    }
    __syncthreads();

    const int j = j0 + t;
    const float* Qrow = &Q[(size_t)(b * SB + j) * AA];

    float acc[8];
    #pragma unroll
    for (int i = 0; i < 8; ++i) acc[i] = 0.f;
    float Vacc = 0.f;

    #pragma unroll 4
    for (int x = 0; x < 32; ++x) {
        const float4 q4 = *(const float4*)&Qrow[x * 4];
        const float4 vv = *(const float4*)&vlds[x * 4];
        Vacc += vv.x + vv.y + vv.z + vv.w;
        #pragma unroll
        for (int i = 0; i < 8; ++i) {
            const float4 p = *(const float4*)&Plds[i][x * 4];
            const float r0 = fast_rcp(fmaf(p.x, q4.x, 1.0f));
            const float r1 = fast_rcp(fmaf(p.y, q4.y, 1.0f));
            const float r2 = fast_rcp(fmaf(p.z, q4.z, 1.0f));
            const float r3 = fast_rcp(fmaf(p.w, q4.w, 1.0f));
            float a = acc[i];
            a = fmaf(vv.x, r0, a);
            a = fmaf(vv.y, r1, a);
            a = fmaf(vv.z, r2, a);
            a = fmaf(vv.w, r3, a);
            acc[i] = a;
        }
    }

    #pragma unroll
    for (int i = 0; i < 8; ++i)
        e_out[(size_t)(b * SB + i0 + i) * SB + j] = Vacc - 2.0f * acc[i];
}

// K2b: in-place row softmax over 1024 elements. grid (2048), 256 threads.
__global__ __launch_bounds__(256) void k2b_softmax(float* __restrict__ attn)
{
    const int row = blockIdx.x;
    float* er = attn + (size_t)row * SB;
    const int t = threadIdx.x;

    float4 ev = *(const float4*)&er[t * 4];
    float m = fmaxf(fmaxf(ev.x, ev.y), fmaxf(ev.z, ev.w));
    #pragma unroll
    for (int off = 32; off > 0; off >>= 1) m = fmaxf(m, __shfl_xor(m, off));

    __shared__ float redm[4];
    __shared__ float reds[4];
    const int wv = t >> 6;
    if ((t & 63) == 0) redm[wv] = m;
    __syncthreads();
    m = fmaxf(fmaxf(redm[0], redm[1]), fmaxf(redm[2], redm[3]));

    const float L2E = 1.4426950408889634f;
    float4 p;
    p.x = fast_ex2((ev.x - m) * L2E);
    p.y = fast_ex2((ev.y - m) * L2E);
    p.z = fast_ex2((ev.z - m) * L2E);
    p.w = fast_ex2((ev.w - m) * L2E);

    float s = p.x + p.y + p.z + p.w;
    #pragma unroll
    for (int off = 32; off > 0; off >>= 1) s += __shfl_xor(s, off);
    if ((t & 63) == 0) reds[wv] = s;
    __syncthreads();
    s = reds[0] + reds[1] + reds[2] + reds[3];

    const float inv = fast_rcp(s);
    p.x *= inv; p.y *= inv; p.z *= inv; p.w *= inv;
    *(float4*)&er[t * 4] = p;
}

// K2c: colw[b,j] = sum_i attn[b,i,j]. grid (4 jchunks, 16 ichunks, 2 b), 256 threads.
__global__ __launch_bounds__(256) void k2c_colsum(const float* __restrict__ attn,
                                                  float* __restrict__ colw)
{
    const int b  = blockIdx.z;
    const int j  = blockIdx.x * 256 + threadIdx.x;
    const int i0 = blockIdx.y * 64;
    const float* base = attn + (size_t)(b * SB + i0) * SB + j;
    float acc = 0.f;
    #pragma unroll 8
    for (int i = 0; i < 64; ++i) acc += base[(size_t)i * SB];
    atomicAdd(&colw[b * SB + j], acc);
}

// K4: ctx[b,h] = sum_j colw[b,j] * lstm[b,j,h]. grid (2 hchunks, 8 jchunks, 2 b), 256 thr.
__global__ __launch_bounds__(256) void k4_context(const float* __restrict__ lstm,
                                                  const float* __restrict__ colw,
                                                  float* __restrict__ ctx)
{
    const int b  = blockIdx.z;
    const int h  = blockIdx.x * 256 + threadIdx.x;
    const int j0 = blockIdx.y * 128;
    __shared__ float cw[128];
    if (threadIdx.x < 128) cw[threadIdx.x] = colw[b * SB + j0 + threadIdx.x];
    __syncthreads();
    float acc = 0.f;
    #pragma unroll 8
    for (int jj = 0; jj < 128; ++jj)
        acc = fmaf(cw[jj], lstm[(size_t)(b * SB + j0 + jj) * HH + h], acc);
    atomicAdd(&ctx[b * HH + h], acc);
}

extern "C" void kernel_launch(void* const* d_in, const int* in_sizes, int n_in,
                              void* d_out, int out_size, void* d_ws, size_t ws_size,
                              hipStream_t stream)
{
    const float* lstm = (const float*)d_in[0];   // (B,S,H)
    const float* w    = (const float*)d_in[1];   // (H,A)
    const float* u    = (const float*)d_in[2];   // (H,A)
    const float* v    = (const float*)d_in[3];   // (A,)

    float* out  = (float*)d_out;
    float* ctx  = out;                     // (B,H)   = 1024 floats
    float* attn = out + BATCH * HH;        // (B,S,S) = 2M floats

    float* P    = (float*)d_ws;                          // B*S*A floats = 1 MB
    float* Qb   = P  + (size_t)BATCH * SB * AA;          // 1 MB
    float* colw = Qb + (size_t)BATCH * SB * AA;          // B*S floats = 8 KB

    hipMemsetAsync(ctx,  0, (size_t)BATCH * HH * sizeof(float), stream);
    hipMemsetAsync(colw, 0, (size_t)BATCH * SB * sizeof(float), stream);

    k1_gemm_exp<<<dim3(64, 8), 256, 0, stream>>>(lstm, w, u, P, Qb);
    k2a_escore<<<dim3(4, 128, BATCH), 256, 0, stream>>>(P, Qb, v, attn);
    k2b_softmax<<<dim3(BATCH * SB), 256, 0, stream>>>(attn);
    k2c_colsum<<<dim3(4, 16, BATCH), 256, 0, stream>>>(attn, colw);
    k4_context<<<dim3(2, 8, BATCH), 256, 0, stream>>>(lstm, colw, ctx);
}

// Round 2
// 89.642 us; speedup vs baseline: 1.0189x; 1.0189x over previous
//
#include <hip/hip_runtime.h>

#define HH   512
#define AA   128
#define SB   1024
#define BATCH 2

__device__ __forceinline__ float fast_rcp(float x) { return __builtin_amdgcn_rcpf(x); }
__device__ __forceinline__ float fast_ex2(float x) { return __builtin_amdgcn_exp2f(x); }

// K1: [P|Q] = exp(2 * lstm(2048x512) @ [w|u](512x256)).
// BM=128, BN=16, BK=16, 256 threads (4 waves). Lane owns 2 m-rows (ds_read_b64,
// 2-way bank alias = free). B columns are wave-uniform -> s_load_dwordx4.
// Double-buffered A tile, 1 barrier per K-chunk. grid (16, 16).
__global__ __launch_bounds__(256) void k1_gemm_exp(const float* __restrict__ lstm,
                                                   const float* __restrict__ w,
                                                   const float* __restrict__ u,
                                                   float* __restrict__ P,
                                                   float* __restrict__ Qm)
{
    __shared__ float As[2][16][128];           // [buf][k][m] k-major
    const int m0   = blockIdx.x * 128;
    const int nblk = blockIdx.y * 16;          // global col 0..255
    const float* __restrict__ Bsrc = (nblk < AA) ? w : u;
    float* __restrict__ Obuf       = (nblk < AA) ? P : Qm;
    const int ncol = nblk & (AA - 1);
    const int t    = threadIdx.x;
    const int lane = t & 63;
    const int n0   = ncol + __builtin_amdgcn_readfirstlane(t >> 6) * 4;  // wave-uniform

    const int sr = t >> 2;                     // 0..63
    const int sq = (t & 3) * 4;                // k-quad 0,4,8,12

    float acc[2][4];
    #pragma unroll
    for (int i = 0; i < 2; ++i)
        #pragma unroll
        for (int c = 0; c < 4; ++c) acc[i][c] = 0.f;

    {   // prologue: stage chunk 0 into buf 0
        const float4 a0 = *(const float4*)&lstm[(size_t)(m0 + sr) * HH + sq];
        const float4 a1 = *(const float4*)&lstm[(size_t)(m0 + sr + 64) * HH + sq];
        As[0][sq+0][sr]    = a0.x; As[0][sq+1][sr]    = a0.y;
        As[0][sq+2][sr]    = a0.z; As[0][sq+3][sr]    = a0.w;
        As[0][sq+0][sr+64] = a1.x; As[0][sq+1][sr+64] = a1.y;
        As[0][sq+2][sr+64] = a1.z; As[0][sq+3][sr+64] = a1.w;
    }
    __syncthreads();

    for (int c = 0; c < 32; ++c) {
        const int cur = c & 1;
        const bool more = (c < 31);
        float4 b0, b1;
        if (more) {
            const int k0n = (c + 1) * 16;
            b0 = *(const float4*)&lstm[(size_t)(m0 + sr) * HH + k0n + sq];
            b1 = *(const float4*)&lstm[(size_t)(m0 + sr + 64) * HH + k0n + sq];
        }
        const int k0 = c * 16;
        #pragma unroll
        for (int k = 0; k < 16; ++k) {
            const float2 a2 = *(const float2*)&As[cur][k][lane * 2];
            const float4 bb = *(const float4*)&Bsrc[(size_t)(k0 + k) * AA + n0]; // s_load
            acc[0][0] = fmaf(a2.x, bb.x, acc[0][0]);
            acc[0][1] = fmaf(a2.x, bb.y, acc[0][1]);
            acc[0][2] = fmaf(a2.x, bb.z, acc[0][2]);
            acc[0][3] = fmaf(a2.x, bb.w, acc[0][3]);
            acc[1][0] = fmaf(a2.y, bb.x, acc[1][0]);
            acc[1][1] = fmaf(a2.y, bb.y, acc[1][1]);
            acc[1][2] = fmaf(a2.y, bb.z, acc[1][2]);
            acc[1][3] = fmaf(a2.y, bb.w, acc[1][3]);
        }
        if (more) {
            const int nxt = cur ^ 1;
            As[nxt][sq+0][sr]    = b0.x; As[nxt][sq+1][sr]    = b0.y;
            As[nxt][sq+2][sr]    = b0.z; As[nxt][sq+3][sr]    = b0.w;
            As[nxt][sq+0][sr+64] = b1.x; As[nxt][sq+1][sr+64] = b1.y;
            As[nxt][sq+2][sr+64] = b1.z; As[nxt][sq+3][sr+64] = b1.w;
            __syncthreads();
        }
    }

    const float KK = 2.8853900817779268f;      // 2 * log2(e)
    const int mrow = m0 + lane * 2;
    #pragma unroll
    for (int mm = 0; mm < 2; ++mm)
        #pragma unroll
        for (int cc = 0; cc < 4; ++cc)
            Obuf[(size_t)(mrow + mm) * AA + n0 + cc] = fast_ex2(KK * acc[mm][cc]);
}

// K2a: E[b,i,j] = exp(e), e = Vsum - 2 * sum_a v[a]/(P[b,i,a]*Q[b,j,a]+1).
// P rows + v are wave-uniform (blockIdx-indexed) -> SGPR s_loads; no LDS.
// Pairwise rcp combine: v0/d0+v1/d1 = (v0*d1+v1*d0)/(d0*d1) halves rcp count.
// grid (4, 128, 2), 256 threads; block = 8 i-rows x 256 j.
__global__ __launch_bounds__(256) void k2a_escore(const float* __restrict__ P,
                                                  const float* __restrict__ Q,
                                                  const float* __restrict__ v,
                                                  float* __restrict__ E)
{
    const int b  = blockIdx.z;
    const int i0 = blockIdx.y * 8;
    const int j  = blockIdx.x * 256 + threadIdx.x;

    const float* __restrict__ Qrow  = &Q[((size_t)b * SB + j) * AA];
    const float* __restrict__ Pbase = &P[((size_t)b * SB + i0) * AA];

    float acc[8];
    #pragma unroll
    for (int i = 0; i < 8; ++i) acc[i] = 0.f;
    float Vacc = 0.f;

    #pragma unroll 2
    for (int x = 0; x < 32; ++x) {
        const float4 q4 = *(const float4*)&Qrow[x * 4];
        const float4 vv = *(const float4*)&v[x * 4];        // s_load (uniform)
        Vacc += (vv.x + vv.y) + (vv.z + vv.w);
        #pragma unroll
        for (int i = 0; i < 8; ++i) {
            const float4 p = *(const float4*)&Pbase[i * AA + x * 4];  // s_load (uniform)
            const float d0 = fmaf(p.x, q4.x, 1.0f);
            const float d1 = fmaf(p.y, q4.y, 1.0f);
            const float d2 = fmaf(p.z, q4.z, 1.0f);
            const float d3 = fmaf(p.w, q4.w, 1.0f);
            const float n0 = fmaf(vv.y, d0, vv.x * d1);
            const float n1 = fmaf(vv.w, d2, vv.z * d3);
            const float r0 = fast_rcp(d0 * d1);
            const float r1 = fast_rcp(d2 * d3);
            acc[i] = fmaf(n0, r0, acc[i]);
            acc[i] = fmaf(n1, r1, acc[i]);
        }
    }

    // e = Vacc - 2*acc; E = exp(e) = exp2(L2E*Vacc - 2*L2E*acc). |e| <= ~9 -> safe.
    const float L2E  = 1.4426950408889634f;
    const float base = Vacc * L2E;
    float* __restrict__ Eout = &E[((size_t)b * SB + i0) * SB + j];
    #pragma unroll
    for (int i = 0; i < 8; ++i)
        Eout[(size_t)i * SB] = fast_ex2(fmaf(acc[i], -2.0f * L2E, base));
}

// K2b: attn = E / rowsum(E), in place (no max pass needed, |e|<=9). grid (2048).
__global__ __launch_bounds__(256) void k2b_rowscale(float* __restrict__ attn)
{
    const int row = blockIdx.x;
    float* __restrict__ er = attn + (size_t)row * SB;
    const int t = threadIdx.x;

    float4 ev = *(const float4*)&er[t * 4];
    float s = (ev.x + ev.y) + (ev.z + ev.w);
    #pragma unroll
    for (int off = 32; off > 0; off >>= 1) s += __shfl_xor(s, off);

    __shared__ float reds[4];
    if ((t & 63) == 0) reds[t >> 6] = s;
    __syncthreads();
    s = (reds[0] + reds[1]) + (reds[2] + reds[3]);

    const float inv = fast_rcp(s);
    ev.x *= inv; ev.y *= inv; ev.z *= inv; ev.w *= inv;
    *(float4*)&er[t * 4] = ev;
}

// K2c: colw[b,j] = sum_i attn[b,i,j]. grid (4, 16, 2), 256 threads.
__global__ __launch_bounds__(256) void k2c_colsum(const float* __restrict__ attn,
                                                  float* __restrict__ colw)
{
    const int b  = blockIdx.z;
    const int j  = blockIdx.x * 256 + threadIdx.x;
    const int i0 = blockIdx.y * 64;
    const float* base = attn + (size_t)(b * SB + i0) * SB + j;
    float acc = 0.f;
    #pragma unroll 8
    for (int i = 0; i < 64; ++i) acc += base[(size_t)i * SB];
    atomicAdd(&colw[b * SB + j], acc);
}

// K4: ctx[b,h] = sum_j colw[b,j] * lstm[b,j,h]. grid (2, 8, 2), 256 threads.
__global__ __launch_bounds__(256) void k4_context(const float* __restrict__ lstm,
                                                  const float* __restrict__ colw,
                                                  float* __restrict__ ctx)
{
    const int b  = blockIdx.z;
    const int h  = blockIdx.x * 256 + threadIdx.x;
    const int j0 = blockIdx.y * 128;
    __shared__ float cw[128];
    if (threadIdx.x < 128) cw[threadIdx.x] = colw[b * SB + j0 + threadIdx.x];
    __syncthreads();
    float acc = 0.f;
    #pragma unroll 8
    for (int jj = 0; jj < 128; ++jj)
        acc = fmaf(cw[jj], lstm[(size_t)(b * SB + j0 + jj) * HH + h], acc);
    atomicAdd(&ctx[b * HH + h], acc);
}

extern "C" void kernel_launch(void* const* d_in, const int* in_sizes, int n_in,
                              void* d_out, int out_size, void* d_ws, size_t ws_size,
                              hipStream_t stream)
{
    const float* lstm = (const float*)d_in[0];   // (B,S,H)
    const float* w    = (const float*)d_in[1];   // (H,A)
    const float* u    = (const float*)d_in[2];   // (H,A)
    const float* v    = (const float*)d_in[3];   // (A,)

    float* out  = (float*)d_out;
    float* ctx  = out;                     // (B,H)   = 1024 floats
    float* attn = out + BATCH * HH;        // (B,S,S) = 2M floats

    float* P    = (float*)d_ws;                          // B*S*A floats = 1 MB
    float* Qb   = P  + (size_t)BATCH * SB * AA;          // 1 MB
    float* colw = Qb + (size_t)BATCH * SB * AA;          // B*S floats = 8 KB

    hipMemsetAsync(ctx,  0, (size_t)BATCH * HH * sizeof(float), stream);
    hipMemsetAsync(colw, 0, (size_t)BATCH * SB * sizeof(float), stream);

    k1_gemm_exp<<<dim3(16, 16), 256, 0, stream>>>(lstm, w, u, P, Qb);
    k2a_escore<<<dim3(4, 128, BATCH), 256, 0, stream>>>(P, Qb, v, attn);
    k2b_rowscale<<<dim3(BATCH * SB), 256, 0, stream>>>(attn);
    k2c_colsum<<<dim3(4, 16, BATCH), 256, 0, stream>>>(attn, colw);
    k4_context<<<dim3(2, 8, BATCH), 256, 0, stream>>>(lstm, colw, ctx);
}

// Round 3
// 62.949 us; speedup vs baseline: 1.4509x; 1.4240x over previous
//
#include <hip/hip_runtime.h>

#define HH   512
#define AA   128
#define SB   1024
#define BATCH 2

__device__ __forceinline__ float fast_rcp(float x) { return __builtin_amdgcn_rcpf(x); }
__device__ __forceinline__ float fast_ex2(float x) { return __builtin_amdgcn_exp2f(x); }

// K1: partial GEMM C = lstm(2048x512) @ [w|u](512x256), K split in 2 halves.
// BM=64, BN=32, BK=32, 256 threads, 4m x 2n per thread. grid (32, 8, 2).
// A staged k-major (lane=row -> <=2-way store conflicts, b128 reads broadcast),
// B staged k-major natural (b128 write, b64 read conflict-free).
// Block (0,0,z) also zeroes colw half z (k2's atomic target).
__global__ __launch_bounds__(256) void k1_gemm(const float* __restrict__ lstm,
                                               const float* __restrict__ w,
                                               const float* __restrict__ u,
                                               float* __restrict__ part0,
                                               float* __restrict__ part1,
                                               float* __restrict__ colw)
{
    __shared__ float As[32][68];   // [k][m], pad 4 -> 272B rows (16B aligned)
    __shared__ float Bs[32][36];   // [k][n], pad 4 -> 144B rows
    const int t  = threadIdx.x;
    const int bx = blockIdx.x, by = blockIdx.y, bz = blockIdx.z;
    const int m0 = bx * 64;
    const int n0 = by * 32;                       // global col 0..255
    const float* __restrict__ Bsrc = (n0 < AA) ? w : u;
    const int ncol = n0 & (AA - 1);

    if (bx == 0 && by == 0) {                      // zero colw (2048 floats total)
        float4 z4; z4.x = z4.y = z4.z = z4.w = 0.f;
        ((float4*)colw)[bz * 256 + t] = z4;
    }

    const int r  = t & 63;                         // staging row
    const int kq = (t >> 6) * 8;                   // wave-uniform k-quad pair
    const int kk = t >> 3;                         // B staging k
    const int nq = (t & 7) * 4;                    // B staging n-quad
    const int tm = t >> 4;                         // 0..15 -> rows 4tm..4tm+3
    const int tn = t & 15;                         // 0..15 -> cols 2tn..2tn+1

    float acc[4][2];
    #pragma unroll
    for (int i = 0; i < 4; ++i) { acc[i][0] = 0.f; acc[i][1] = 0.f; }

    for (int kc = 0; kc < 8; ++kc) {
        const int k0 = bz * 256 + kc * 32;
        const float* ap = &lstm[(size_t)(m0 + r) * HH + k0 + kq];
        const float4 a0 = *(const float4*)&ap[0];
        const float4 a1 = *(const float4*)&ap[4];
        As[kq + 0][r] = a0.x; As[kq + 1][r] = a0.y;
        As[kq + 2][r] = a0.z; As[kq + 3][r] = a0.w;
        As[kq + 4][r] = a1.x; As[kq + 5][r] = a1.y;
        As[kq + 6][r] = a1.z; As[kq + 7][r] = a1.w;
        const float4 bv = *(const float4*)&Bsrc[(size_t)(k0 + kk) * AA + ncol + nq];
        *(float4*)&Bs[kk][nq] = bv;
        __syncthreads();
        #pragma unroll
        for (int k = 0; k < 32; ++k) {
            const float4 av = *(const float4*)&As[k][4 * tm];
            const float2 bb = *(const float2*)&Bs[k][2 * tn];
            acc[0][0] = fmaf(av.x, bb.x, acc[0][0]);
            acc[0][1] = fmaf(av.x, bb.y, acc[0][1]);
            acc[1][0] = fmaf(av.y, bb.x, acc[1][0]);
            acc[1][1] = fmaf(av.y, bb.y, acc[1][1]);
            acc[2][0] = fmaf(av.z, bb.x, acc[2][0]);
            acc[2][1] = fmaf(av.z, bb.y, acc[2][1]);
            acc[3][0] = fmaf(av.w, bb.x, acc[3][0]);
            acc[3][1] = fmaf(av.w, bb.y, acc[3][1]);
        }
        __syncthreads();
    }

    float* __restrict__ part = bz ? part1 : part0;
    #pragma unroll
    for (int mi = 0; mi < 4; ++mi) {
        float2 st; st.x = acc[mi][0]; st.y = acc[mi][1];
        *(float2*)&part[(size_t)(m0 + 4 * tm + mi) * 256 + n0 + 2 * tn] = st;
    }
}

// K1b: [P|Q] = exp2(KK * (part0 + part1)). grid (512), 256 threads, float4/thread.
__global__ __launch_bounds__(256) void k1b_combine_exp(const float* __restrict__ part0,
                                                       const float* __restrict__ part1,
                                                       float* __restrict__ P,
                                                       float* __restrict__ Q)
{
    const float KK = 2.8853900817779268f;          // 2 * log2(e)
    const int idx = blockIdx.x * 256 + threadIdx.x;  // 0..131071 float4s
    const float4 c0 = ((const float4*)part0)[idx];
    const float4 c1 = ((const float4*)part1)[idx];
    float4 o;
    o.x = fast_ex2(KK * (c0.x + c1.x));
    o.y = fast_ex2(KK * (c0.y + c1.y));
    o.z = fast_ex2(KK * (c0.z + c1.z));
    o.w = fast_ex2(KK * (c0.w + c1.w));
    const int m  = idx >> 6;                        // row 0..2047
    const int qd = idx & 63;                        // float4 within 256-col row
    float* dst = (qd < 32) ? &P[(size_t)m * AA + qd * 4]
                           : &Q[(size_t)m * AA + (qd - 32) * 4];
    *(float4*)dst = o;
}

// K2: fused e-score + softmax + colsum.
// Block = 8 i-rows x all 1024 j; 1024 threads, 1 j each. grid (128, 2).
// E[b,i,j] = exp(Vsum - 2*sum_a v[a]/(P[i,a]*Q[j,a]+1)) kept in regs, row-sums
// reduced in-block, normalized attn written once, colw accumulated via atomics.
// P rows + v are wave-uniform -> SGPR s_loads. Block x==0 zeroes ctx (for k4).
__global__ __launch_bounds__(1024) void k2_fused(const float* __restrict__ P,
                                                 const float* __restrict__ Q,
                                                 const float* __restrict__ v,
                                                 float* __restrict__ attn,
                                                 float* __restrict__ colw,
                                                 float* __restrict__ ctx)
{
    const int b  = blockIdx.y;
    const int i0 = blockIdx.x * 8;
    const int j  = threadIdx.x;

    if (blockIdx.x == 0 && j < HH) ctx[b * HH + j] = 0.f;   // k4 runs after k2

    const float* __restrict__ Qrow = &Q[((size_t)b * SB + j) * AA];
    const float* __restrict__ Pb   = &P[((size_t)b * SB + i0) * AA];

    float acc[8];
    #pragma unroll
    for (int i = 0; i < 8; ++i) acc[i] = 0.f;
    float Vacc = 0.f;

    #pragma unroll 2
    for (int x = 0; x < 32; ++x) {
        const float4 q4 = *(const float4*)&Qrow[x * 4];
        const float4 vv = *(const float4*)&v[x * 4];            // s_load (uniform)
        Vacc += (vv.x + vv.y) + (vv.z + vv.w);
        #pragma unroll
        for (int i = 0; i < 8; ++i) {
            const float4 p = *(const float4*)&Pb[i * AA + x * 4]; // s_load (uniform)
            const float d0 = fmaf(p.x, q4.x, 1.0f);
            const float d1 = fmaf(p.y, q4.y, 1.0f);
            const float d2 = fmaf(p.z, q4.z, 1.0f);
            const float d3 = fmaf(p.w, q4.w, 1.0f);
            const float na = fmaf(vv.y, d0, vv.x * d1);
            const float nb = fmaf(vv.w, d2, vv.z * d3);
            const float ra = fast_rcp(d0 * d1);
            const float rb = fast_rcp(d2 * d3);
            acc[i] = fmaf(na, ra, acc[i]);
            acc[i] = fmaf(nb, rb, acc[i]);
        }
    }

    const float L2E  = 1.4426950408889634f;
    const float base = Vacc * L2E;
    float E[8];
    #pragma unroll
    for (int i = 0; i < 8; ++i)
        E[i] = fast_ex2(fmaf(acc[i], -2.0f * L2E, base));

    // cross-thread row sums (8 rows x 1024 threads): wave reduce -> LDS -> all
    __shared__ float red[8][16];
    const int lane = j & 63, wv = j >> 6;
    #pragma unroll
    for (int i = 0; i < 8; ++i) {
        float s = E[i];
        #pragma unroll
        for (int off = 32; off > 0; off >>= 1) s += __shfl_xor(s, off);
        if (lane == 0) red[i][wv] = s;
    }
    __syncthreads();

    float csum = 0.f;
    float* __restrict__ arow = &attn[((size_t)b * SB + i0) * SB + j];
    #pragma unroll
    for (int i = 0; i < 8; ++i) {
        const float4* rr = (const float4*)red[i];
        const float4 r0 = rr[0], r1 = rr[1], r2 = rr[2], r3 = rr[3];
        const float rs = ((r0.x + r0.y) + (r0.z + r0.w)) + ((r1.x + r1.y) + (r1.z + r1.w))
                       + ((r2.x + r2.y) + (r2.z + r2.w)) + ((r3.x + r3.y) + (r3.z + r3.w));
        const float a = E[i] * fast_rcp(rs);
        arow[(size_t)i * SB] = a;
        csum += a;
    }
    atomicAdd(&colw[b * SB + j], csum);
}

// K4: ctx[b,h] = sum_j colw[b,j] * lstm[b,j,h]. grid (2, 8, 2), 256 threads.
__global__ __launch_bounds__(256) void k4_context(const float* __restrict__ lstm,
                                                  const float* __restrict__ colw,
                                                  float* __restrict__ ctx)
{
    const int b  = blockIdx.z;
    const int h  = blockIdx.x * 256 + threadIdx.x;
    const int j0 = blockIdx.y * 128;
    __shared__ float cw[128];
    if (threadIdx.x < 128) cw[threadIdx.x] = colw[b * SB + j0 + threadIdx.x];
    __syncthreads();
    float acc = 0.f;
    #pragma unroll 8
    for (int jj = 0; jj < 128; ++jj)
        acc = fmaf(cw[jj], lstm[(size_t)(b * SB + j0 + jj) * HH + h], acc);
    atomicAdd(&ctx[b * HH + h], acc);
}

extern "C" void kernel_launch(void* const* d_in, const int* in_sizes, int n_in,
                              void* d_out, int out_size, void* d_ws, size_t ws_size,
                              hipStream_t stream)
{
    const float* lstm = (const float*)d_in[0];   // (B,S,H)
    const float* w    = (const float*)d_in[1];   // (H,A)
    const float* u    = (const float*)d_in[2];   // (H,A)
    const float* v    = (const float*)d_in[3];   // (A,)

    float* out  = (float*)d_out;
    float* ctx  = out;                     // (B,H)   = 1024 floats
    float* attn = out + BATCH * HH;        // (B,S,S) = 2M floats

    float* part0 = (float*)d_ws;                              // 2048*256 = 2 MB
    float* part1 = part0 + (size_t)2048 * 256;                // 2 MB
    float* P     = part1 + (size_t)2048 * 256;                // 1 MB
    float* Qb    = P     + (size_t)BATCH * SB * AA;           // 1 MB
    float* colw  = Qb    + (size_t)BATCH * SB * AA;           // 8 KB

    k1_gemm<<<dim3(32, 8, 2), 256, 0, stream>>>(lstm, w, u, part0, part1, colw);
    k1b_combine_exp<<<dim3(512), 256, 0, stream>>>(part0, part1, P, Qb);
    k2_fused<<<dim3(128, BATCH), 1024, 0, stream>>>(P, Qb, v, attn, colw, ctx);
    k4_context<<<dim3(2, 8, BATCH), 256, 0, stream>>>(lstm, colw, ctx);
}